// Round 19
// baseline (458.959 us; speedup 1.0000x reference)
//
#include <hip/hip_runtime.h>
#include <math.h>

#define N_NODES 100000
#define N_EDGES 1000000
#define HID     64
#define HIER    32
#define NDIM    128
#define EDIM    32
#define K1      96    // HIER + HID
#define C1      128   // 2*HID
#define NCLS    10
#define BN_EPS  1e-5f
#define SCAN_B  98    // ceil(N_NODES/1024)
#define ZSTRIPS 6250  // N_NODES / 16
#define CONV_E_BLOCKS 15625   // 4M threads, 8 floats each
#define CONV_C_BLOCKS 3125    // N*8 float4s / 256

typedef __attribute__((ext_vector_type(8))) short short8;
typedef __attribute__((ext_vector_type(4))) float f32x4;

// pack two f32 -> (bf16(a) | bf16(b)<<16), round-to-nearest-even
__device__ __forceinline__ unsigned pk_bf16(float a, float b) {
    unsigned ua = __float_as_uint(a);
    ua = (ua + 0x7FFFu + ((ua >> 16) & 1u)) >> 16;
    unsigned ub = __float_as_uint(b);
    ub = (ub + 0x7FFFu + ((ub >> 16) & 1u)) & 0xFFFF0000u;
    return ua | ub;
}
__device__ __forceinline__ float bf_lo(unsigned g) { return __uint_as_float(g << 16); }
__device__ __forceinline__ float bf_hi(unsigned g) { return __uint_as_float(g & 0xFFFF0000u); }
__device__ __forceinline__ short8 as_s8(uint4 u) {
    union { uint4 u; short8 s; } c; c.u = u; return c.s;
}

// ---------------- CSR build ----------------

__global__ void k_count(const int* __restrict__ ei, int* __restrict__ cnt) {
    int i = blockIdx.x * blockDim.x + threadIdx.x;
    if (i < N_EDGES) atomicAdd(&cnt[ei[N_EDGES + i]], 1);
}

__global__ void k_scan1(const int* __restrict__ cnt, int* __restrict__ offs,
                        float* __restrict__ dinv, int* __restrict__ bsum) {
    __shared__ int buf[2][1024];
    int t = threadIdx.x, b = blockIdx.x;
    int i = b * 1024 + t;
    int v = (i < N_NODES) ? cnt[i] : 0;
    buf[0][t] = v; __syncthreads();
    int pi = 0;
    for (int off = 1; off < 1024; off <<= 1) {
        int x = buf[pi][t];
        if (t >= off) x += buf[pi][t - off];
        buf[pi ^ 1][t] = x; __syncthreads(); pi ^= 1;
    }
    int incl = buf[pi][t];
    if (i < N_NODES) {
        offs[i] = incl - v;
        dinv[i] = rsqrtf((float)(v + 1));
    }
    if (t == 1023) bsum[b] = incl;
}

__global__ void k_scan2(int* __restrict__ bsum, int nb) {
    __shared__ int buf[2][1024];
    int t = threadIdx.x;
    int v = (t < nb) ? bsum[t] : 0;
    buf[0][t] = v; __syncthreads();
    int pi = 0;
    for (int off = 1; off < 1024; off <<= 1) {
        int x = buf[pi][t];
        if (t >= off) x += buf[pi][t - off];
        buf[pi ^ 1][t] = x; __syncthreads(); pi ^= 1;
    }
    int incl = buf[pi][t];
    if (t < nb) bsum[t] = incl - v;
}

// also pre-initializes cursor = offs (k_fill then needs ONE random access/edge)
__global__ void k_scan3(const int* __restrict__ bsum, int* __restrict__ offs,
                        int* __restrict__ cursor) {
    int b = blockIdx.x;
    int i = b * 1024 + threadIdx.x;
    if (i < N_NODES) {
        int v = offs[i] + bsum[b];
        offs[i] = v;
        cursor[i] = v;
    }
    if (i == 0) offs[N_NODES] = N_EDGES;
}

// packed CSR record (8B): x = eid(20b) | src_low12 << 20 ; y = src_hi5 | norm_bf16 << 16
__global__ void k_fill(const int* __restrict__ ei, int* __restrict__ cursor,
                       const float* __restrict__ dinv, uint2* __restrict__ epk) {
    int i = blockIdx.x * blockDim.x + threadIdx.x;
    if (i >= N_EDGES) return;
    int s = ei[i], d = ei[N_EDGES + i];
    int pos = atomicAdd(&cursor[d], 1);
    unsigned nhi = pk_bf16(dinv[s], 0.f) << 16;
    epk[pos] = make_uint2((unsigned)i | ((unsigned)(s & 0xFFF) << 20),
                          nhi | (unsigned)(s >> 12));
}

// ---------------- merged streaming converts: e -> ebf, c -> cbf ----------------

__global__ __launch_bounds__(256) void k_convm(const float4* __restrict__ e4,
                                               uint4* __restrict__ eb4,
                                               const float4* __restrict__ c4,
                                               uint2* __restrict__ cb2) {
    int b = blockIdx.x;
    if (b < CONV_E_BLOCKS) {
        int i = b * 256 + threadIdx.x;
        float4 a = e4[(size_t)2 * i];
        float4 bb = e4[(size_t)2 * i + 1];
        uint4 pk;
        pk.x = pk_bf16(a.x, a.y); pk.y = pk_bf16(a.z, a.w);
        pk.z = pk_bf16(bb.x, bb.y); pk.w = pk_bf16(bb.z, bb.w);
        eb4[i] = pk;
    } else {
        int i = (b - CONV_E_BLOCKS) * 256 + threadIdx.x;
        if (i < N_NODES * 8) {
            float4 a = c4[i];
            cb2[i] = make_uint2(pk_bf16(a.x, a.y), pk_bf16(a.z, a.w));
        }
    }
}

// w1 [96][128] -> bpkg (12 groups x 128 cols); w_node [128][64] -> bpkn (16 x 64).
__global__ void k_wpack(const float* __restrict__ w1, const float* __restrict__ wn,
                        uint4* __restrict__ bpkg, uint4* __restrict__ bpkn) {
    for (int i = threadIdx.x; i < 12 * C1 + 16 * HID; i += 256) {
        if (i < 12 * C1) {
            int g = i >> 7, n = i & 127;
            uint4 r;
            r.x = pk_bf16(w1[(8 * g + 0) * C1 + n], w1[(8 * g + 1) * C1 + n]);
            r.y = pk_bf16(w1[(8 * g + 2) * C1 + n], w1[(8 * g + 3) * C1 + n]);
            r.z = pk_bf16(w1[(8 * g + 4) * C1 + n], w1[(8 * g + 5) * C1 + n]);
            r.w = pk_bf16(w1[(8 * g + 6) * C1 + n], w1[(8 * g + 7) * C1 + n]);
            bpkg[i] = r;
        } else {
            int j = i - 12 * C1;
            int g = j >> 6, n = j & 63;
            int kb = (g >> 2) * 32 + (g & 3) * 8;
            uint4 r;
            r.x = pk_bf16(wn[(kb + 0) * HID + n], wn[(kb + 1) * HID + n]);
            r.y = pk_bf16(wn[(kb + 2) * HID + n], wn[(kb + 3) * HID + n]);
            r.z = pk_bf16(wn[(kb + 4) * HID + n], wn[(kb + 5) * HID + n]);
            r.w = pk_bf16(wn[(kb + 6) * HID + n], wn[(kb + 7) * HID + n]);
            bpkn[j] = r;
        }
    }
}

// ---------------- fused edge aggregation + se ----------------
// Block = 16 nodes. Phase 1 (quarter-wave gather) -> agg rows in LDS.
// Phase 2: se = agg @ w_edge + wsum*b_edge in-block (w_edge in LDS),
// written packed bf16. NOTE: sebf must NOT alias ebf (reads are concurrent).

__global__ __launch_bounds__(256) void k_aggse(const unsigned* __restrict__ ebfu,
                                               const uint2* __restrict__ epk,
                                               const int* __restrict__ offs,
                                               const float* __restrict__ dinv,
                                               const float* __restrict__ we,
                                               const float* __restrict__ be,
                                               unsigned* __restrict__ sebf) {
    __shared__ float aggT[16][33];
    __shared__ float wsum[16];
    __shared__ float wes[EDIM * HID];   // 8 KB
    __shared__ float bes[HID];
    int tid = threadIdx.x;
    for (int i = tid; i < EDIM * HID; i += 256) wes[i] = we[i];
    if (tid < HID) bes[tid] = be[tid];
    int node = tid >> 4, q = tid & 15;
    int v = blockIdx.x * 16 + node;            // grid = 6250 -> always < N_NODES
    int start = offs[v], end = offs[v + 1];
    float ax = 0.f, ay = 0.f, wacc = 0.f;
    for (int i = start; i < end; i += 4) {
        int i1 = i + 1, i2 = i + 2, i3 = i + 3;
        uint2 p0 = epk[i];
        uint2 p1 = (i1 < end) ? epk[i1] : make_uint2(0u, 0u);
        uint2 p2 = (i2 < end) ? epk[i2] : make_uint2(0u, 0u);
        uint2 p3 = (i3 < end) ? epk[i3] : make_uint2(0u, 0u);
        float n0 = bf_hi(p0.y), n1 = bf_hi(p1.y);
        float n2 = bf_hi(p2.y), n3 = bf_hi(p3.y);
        unsigned g0 = ebfu[(size_t)(p0.x & 0xFFFFFu) * 16 + q];
        unsigned g1 = ebfu[(size_t)(p1.x & 0xFFFFFu) * 16 + q];
        unsigned g2 = ebfu[(size_t)(p2.x & 0xFFFFFu) * 16 + q];
        unsigned g3 = ebfu[(size_t)(p3.x & 0xFFFFFu) * 16 + q];
        ax += n0 * bf_lo(g0) + n1 * bf_lo(g1) + n2 * bf_lo(g2) + n3 * bf_lo(g3);
        ay += n0 * bf_hi(g0) + n1 * bf_hi(g1) + n2 * bf_hi(g2) + n3 * bf_hi(g3);
        wacc += n0 + n1 + n2 + n3;
    }
    float dv = dinv[v];
    aggT[node][2 * q]     = dv * ax;
    aggT[node][2 * q + 1] = dv * ay;
    if (q == 0) wsum[node] = dv * wacc;
    __syncthreads();
    // phase 2: this thread computes se outputs n0..n0+3 for its node
    int n0 = q * 4;
    float ws_ = wsum[node];
    float o0 = ws_ * bes[n0],     o1 = ws_ * bes[n0 + 1];
    float o2 = ws_ * bes[n0 + 2], o3 = ws_ * bes[n0 + 3];
    #pragma unroll
    for (int k = 0; k < EDIM; ++k) {
        float a = aggT[node][k];
        const float* wr = &wes[k * HID + n0];
        o0 += a * wr[0]; o1 += a * wr[1]; o2 += a * wr[2]; o3 += a * wr[3];
    }
    *(uint2*)&sebf[(size_t)v * 32 + q * 2] =
        make_uint2(pk_bf16(o0, o1), pk_bf16(o2, o3));
}

// ---------------- node encoder via MFMA: hb0 = bf16(x @ w_node + b) ----------------

__global__ __launch_bounds__(256) void k_h0m(const float* __restrict__ x,
                                             const uint4* __restrict__ bpkn,
                                             const float* __restrict__ bias,
                                             unsigned* __restrict__ hbf) {
    int tid = threadIdx.x;
    int wave = tid >> 6, lane = tid & 63;
    int l15 = lane & 15, lg = lane >> 4;
    int strip = blockIdx.x * 4 + wave;
    if (strip >= ZSTRIPS) return;
    int row = strip * 16 + l15;
    short8 A[4];
    #pragma unroll
    for (int kb = 0; kb < 4; ++kb) {
        const float4* xp = (const float4*)&x[(size_t)row * NDIM + kb * 32 + lg * 8];
        float4 a = xp[0], b = xp[1];
        uint4 u;
        u.x = pk_bf16(a.x, a.y); u.y = pk_bf16(a.z, a.w);
        u.z = pk_bf16(b.x, b.y); u.w = pk_bf16(b.z, b.w);
        A[kb] = as_s8(u);
    }
    int rb = strip * 16 + lg * 4;
    #pragma unroll
    for (int ct = 0; ct < 4; ++ct) {
        int n = ct * 16 + l15;
        f32x4 acc = {0.f, 0.f, 0.f, 0.f};
        #pragma unroll
        for (int kb = 0; kb < 4; ++kb) {
            short8 B = as_s8(bpkn[(kb * 4 + lg) * HID + n]);
            acc = __builtin_amdgcn_mfma_f32_16x16x32_bf16(A[kb], B, acc, 0, 0, 0);
        }
        float bn = bias[n];
        #pragma unroll
        for (int i = 0; i < 4; ++i) {
            float hv = acc[i] + bn;
            float ph = __shfl_xor(hv, 1);
            if ((l15 & 1) == 0)
                hbf[(size_t)(rb + i) * 32 + (n >> 1)] = pk_bf16(hv, ph);
        }
    }
}

// ---------------- GCN layer (quarter-wave: 4 nodes/wave, uint2 lanes, unroll 8) ----------------

__device__ __forceinline__ int dec_src(uint2 p) {
    return (int)(((p.y & 0xFFFFu) << 12) | (p.x >> 20));
}

__global__ __launch_bounds__(256) void k_layer4(const unsigned* __restrict__ hold,
                                                const unsigned* __restrict__ sebf,
                                                const uint2* __restrict__ epk,
                                                const int* __restrict__ offs,
                                                const float* __restrict__ dinv,
                                                unsigned* __restrict__ hnew) {
    int v = (blockIdx.x * 256 + threadIdx.x) >> 4;
    if (v >= N_NODES) return;
    int q = threadIdx.x & 15;                 // uint2 index: dims 4q..4q+3
    int start = offs[v], end = offs[v + 1];
    float dv = dinv[v];
    size_t vp = (size_t)v * 16 + q;
    uint2 hv = ((const uint2*)hold)[vp];
    float a0 = dv * bf_lo(hv.x), a1 = dv * bf_hi(hv.x);
    float a2 = dv * bf_lo(hv.y), a3 = dv * bf_hi(hv.y);
    for (int i = start; i < end; i += 8) {
        int idx[8]; float nn[8]; uint2 gg[8];
        #pragma unroll
        for (int u = 0; u < 8; ++u) {
            int ii = i + u;
            uint2 p = (ii < end) ? epk[ii] : make_uint2(0u, 0u);
            idx[u] = dec_src(p);
            nn[u]  = bf_hi(p.y);
        }
        #pragma unroll
        for (int u = 0; u < 8; ++u) gg[u] = ((const uint2*)hold)[(size_t)idx[u] * 16 + q];
        #pragma unroll
        for (int u = 0; u < 8; ++u) {
            a0 += nn[u] * bf_lo(gg[u].x); a1 += nn[u] * bf_hi(gg[u].x);
            a2 += nn[u] * bf_lo(gg[u].y); a3 += nn[u] * bf_hi(gg[u].y);
        }
    }
    uint2 sv = ((const uint2*)sebf)[vp];
    float r0 = bf_lo(sv.x) + dv * a0;
    float r1 = bf_hi(sv.x) + dv * a1;
    float r2 = bf_lo(sv.y) + dv * a2;
    float r3 = bf_hi(sv.y) + dv * a3;
    r0 = (r0 > 0.f) ? r0 : 0.2f * r0;
    r1 = (r1 > 0.f) ? r1 : 0.2f * r1;
    r2 = (r2 > 0.f) ? r2 : 0.2f * r2;
    r3 = (r3 > 0.f) ? r3 : 0.2f * r3;
    ((uint2*)hnew)[vp] = make_uint2(pk_bf16(r0, r1), pk_bf16(r2, r3));
}

// layer 3 variant: also emits hsbf = bf16(h0 + h1 + h2 + h3)
__global__ __launch_bounds__(256) void k_layer4s(const unsigned* __restrict__ hold, // = h2
                                                 const unsigned* __restrict__ hb0,
                                                 const unsigned* __restrict__ hb1,
                                                 const unsigned* __restrict__ sebf,
                                                 const uint2* __restrict__ epk,
                                                 const int* __restrict__ offs,
                                                 const float* __restrict__ dinv,
                                                 unsigned* __restrict__ hnew,
                                                 unsigned* __restrict__ hsbf) {
    int v = (blockIdx.x * 256 + threadIdx.x) >> 4;
    if (v >= N_NODES) return;
    int q = threadIdx.x & 15;
    int start = offs[v], end = offs[v + 1];
    float dv = dinv[v];
    size_t vp = (size_t)v * 16 + q;
    uint2 hv = ((const uint2*)hold)[vp];
    float a0 = dv * bf_lo(hv.x), a1 = dv * bf_hi(hv.x);
    float a2 = dv * bf_lo(hv.y), a3 = dv * bf_hi(hv.y);
    for (int i = start; i < end; i += 8) {
        int idx[8]; float nn[8]; uint2 gg[8];
        #pragma unroll
        for (int u = 0; u < 8; ++u) {
            int ii = i + u;
            uint2 p = (ii < end) ? epk[ii] : make_uint2(0u, 0u);
            idx[u] = dec_src(p);
            nn[u]  = bf_hi(p.y);
        }
        #pragma unroll
        for (int u = 0; u < 8; ++u) gg[u] = ((const uint2*)hold)[(size_t)idx[u] * 16 + q];
        #pragma unroll
        for (int u = 0; u < 8; ++u) {
            a0 += nn[u] * bf_lo(gg[u].x); a1 += nn[u] * bf_hi(gg[u].x);
            a2 += nn[u] * bf_lo(gg[u].y); a3 += nn[u] * bf_hi(gg[u].y);
        }
    }
    uint2 sv = ((const uint2*)sebf)[vp];
    float r0 = bf_lo(sv.x) + dv * a0;
    float r1 = bf_hi(sv.x) + dv * a1;
    float r2 = bf_lo(sv.y) + dv * a2;
    float r3 = bf_hi(sv.y) + dv * a3;
    r0 = (r0 > 0.f) ? r0 : 0.2f * r0;
    r1 = (r1 > 0.f) ? r1 : 0.2f * r1;
    r2 = (r2 > 0.f) ? r2 : 0.2f * r2;
    r3 = (r3 > 0.f) ? r3 : 0.2f * r3;
    ((uint2*)hnew)[vp] = make_uint2(pk_bf16(r0, r1), pk_bf16(r2, r3));
    uint2 g0 = ((const uint2*)hb0)[vp];
    uint2 g1 = ((const uint2*)hb1)[vp];
    float s0 = r0 + bf_lo(g0.x) + bf_lo(g1.x) + bf_lo(hv.x);
    float s1 = r1 + bf_hi(g0.x) + bf_hi(g1.x) + bf_hi(hv.x);
    float s2 = r2 + bf_lo(g0.y) + bf_lo(g1.y) + bf_lo(hv.y);
    float s3 = r3 + bf_hi(g0.y) + bf_hi(g1.y) + bf_hi(hv.y);
    ((uint2*)hsbf)[vp] = make_uint2(pk_bf16(s0, s1), pk_bf16(s2, s3));
}

// ---------------- z GEMM + BN stats via MFMA (verified R15) ----------------

__global__ __launch_bounds__(256) void k_zmfma(const unsigned* __restrict__ hsbf,
                                               const unsigned* __restrict__ cbf,
                                               const uint4* __restrict__ bpkg,
                                               const float* __restrict__ b1,
                                               unsigned* __restrict__ zbf,
                                               float* __restrict__ stats) {
    __shared__ float red[2][4][C1];   // 4 KB
    int tid = threadIdx.x;
    int wave = tid >> 6, lane = tid & 63;
    int l15 = lane & 15, lg = lane >> 4;
    int strip = blockIdx.x * 4 + wave;
    float sN[8], qN[8];
    #pragma unroll
    for (int j = 0; j < 8; ++j) { sN[j] = 0.f; qN[j] = 0.f; }
    if (strip < ZSTRIPS) {
        int row = strip * 16 + l15;
        short8 A0 = as_s8(*(const uint4*)&hsbf[(size_t)row * 32 + lg * 4]);       // k 0..31
        short8 A1 = as_s8(*(const uint4*)&hsbf[(size_t)row * 32 + 16 + lg * 4]);  // k 32..63
        short8 A2 = as_s8(*(const uint4*)&cbf[(size_t)row * 16 + lg * 4]);        // k 64..95
        int rb = strip * 16 + lg * 4;
        #pragma unroll
        for (int ct = 0; ct < 8; ++ct) {
            int n = ct * 16 + l15;
            short8 B0 = as_s8(bpkg[lg * C1 + n]);
            short8 B1 = as_s8(bpkg[(4 + lg) * C1 + n]);
            short8 B2 = as_s8(bpkg[(8 + lg) * C1 + n]);
            f32x4 acc = {0.f, 0.f, 0.f, 0.f};
            acc = __builtin_amdgcn_mfma_f32_16x16x32_bf16(A0, B0, acc, 0, 0, 0);
            acc = __builtin_amdgcn_mfma_f32_16x16x32_bf16(A1, B1, acc, 0, 0, 0);
            acc = __builtin_amdgcn_mfma_f32_16x16x32_bf16(A2, B2, acc, 0, 0, 0);
            float bias = b1[n];
            #pragma unroll
            for (int i = 0; i < 4; ++i) {
                float zz = acc[i] + bias;
                sN[ct] += zz; qN[ct] += zz * zz;
                float pz = __shfl_xor(zz, 1);
                if ((l15 & 1) == 0)
                    zbf[(size_t)(rb + i) * 64 + (n >> 1)] = pk_bf16(zz, pz);
            }
        }
    }
    #pragma unroll
    for (int j = 0; j < 8; ++j) {
        sN[j] += __shfl_xor(sN[j], 16); sN[j] += __shfl_xor(sN[j], 32);
        qN[j] += __shfl_xor(qN[j], 16); qN[j] += __shfl_xor(qN[j], 32);
    }
    if (lane < 16) {
        #pragma unroll
        for (int ct = 0; ct < 8; ++ct) {
            red[0][wave][ct * 16 + lane] = sN[ct];
            red[1][wave][ct * 16 + lane] = qN[ct];
        }
    }
    __syncthreads();
    if (tid < C1) {
        atomicAdd(&stats[tid],
                  red[0][0][tid] + red[0][1][tid] + red[0][2][tid] + red[0][3][tid]);
        atomicAdd(&stats[C1 + tid],
                  red[1][0][tid] + red[1][1][tid] + red[1][2][tid] + red[1][3][tid]);
    }
}

__global__ void k_ab(const float* __restrict__ stats, const float* __restrict__ gamma,
                     const float* __restrict__ beta, float* __restrict__ ab) {
    int t = threadIdx.x;
    if (t < C1) {
        float mu = stats[t] / (float)N_NODES;
        float var = stats[C1 + t] / (float)N_NODES - mu * mu;
        float inv = rsqrtf(var + BN_EPS);
        float a = gamma[t] * inv;
        ab[t] = a;
        ab[C1 + t] = beta[t] - mu * a;
    }
}

// ---------------- output: 4 threads/node (32 dims each), shfl-reduce ----------------

__global__ __launch_bounds__(256) void k_out4(const unsigned* __restrict__ zbf,
                                              const float* __restrict__ ab,
                                              const float* __restrict__ pa,
                                              const float* __restrict__ w2,
                                              const float* __restrict__ b2,
                                              float* __restrict__ out) {
    int gid = blockIdx.x * 256 + threadIdx.x;
    int v = gid >> 2, qq = gid & 3;        // quarter: dims 32*qq .. 32*qq+31
    if (v >= N_NODES) return;
    float alpha = pa[0];
    float acc[NCLS];
    #pragma unroll
    for (int j = 0; j < NCLS; ++j) acc[j] = 0.f;
    const uint4* zr = (const uint4*)(zbf + (size_t)v * 64) + qq * 4;
    #pragma unroll
    for (int t4 = 0; t4 < 4; ++t4) {
        uint4 g = zr[t4];
        unsigned gw[4] = {g.x, g.y, g.z, g.w};
        #pragma unroll
        for (int w = 0; w < 4; ++w) {
            int d0 = qq * 32 + t4 * 8 + w * 2;
            float p0 = bf_lo(gw[w]) * ab[d0]     + ab[C1 + d0];
            float p1 = bf_hi(gw[w]) * ab[d0 + 1] + ab[C1 + d0 + 1];
            p0 = (p0 > 0.f) ? p0 : alpha * p0;
            p1 = (p1 > 0.f) ? p1 : alpha * p1;
            #pragma unroll
            for (int j = 0; j < NCLS; ++j)
                acc[j] += p0 * w2[d0 * NCLS + j] + p1 * w2[(d0 + 1) * NCLS + j];
        }
    }
    #pragma unroll
    for (int j = 0; j < NCLS; ++j) {
        acc[j] += __shfl_xor(acc[j], 1);
        acc[j] += __shfl_xor(acc[j], 2);
    }
    if (qq == 0) {
        #pragma unroll
        for (int j = 0; j < NCLS; ++j) out[(size_t)v * NCLS + j] = acc[j] + b2[j];
    }
}

// ---------------- host ----------------

extern "C" void kernel_launch(void* const* d_in, const int* in_sizes, int n_in,
                              void* d_out, int out_size, void* d_ws, size_t ws_size,
                              hipStream_t stream) {
    const float* x      = (const float*)d_in[0];
    const float* e      = (const float*)d_in[1];
    const float* c      = (const float*)d_in[2];
    const float* w_node = (const float*)d_in[3];
    const float* b_node = (const float*)d_in[4];
    const float* w_edge = (const float*)d_in[5];
    const float* b_edge = (const float*)d_in[6];
    const float* w_out1 = (const float*)d_in[7];
    const float* b_out1 = (const float*)d_in[8];
    const float* gamma  = (const float*)d_in[9];
    const float* beta   = (const float*)d_in[10];
    const float* pa     = (const float*)d_in[11];
    const float* w_out2 = (const float*)d_in[12];
    const float* b_out2 = (const float*)d_in[13];
    const int*   ei     = (const int*)d_in[14];
    float* out = (float*)d_out;

    char* wsb = (char*)d_ws;
    // Region A (64MB): ebf [bf16 1M x 32] eid order; LIVE until k_aggse completes.
    //   zbf (25.6MB) overlays region A at offset 0 (written in k_zmfma, after
    //   ebf is dead). sebf gets its OWN allocation (k_aggse writes it while
    //   other blocks still read ebf -- must not alias!).
    ushort*   ebf  = (ushort*)wsb;
    unsigned* zbf  = (unsigned*)wsb;
    size_t off = (64000000 + 255) & ~(size_t)255;
    auto alloc = [&](size_t bytes) {
        void* p = wsb + off;
        off = (off + bytes + 255) & ~(size_t)255;
        return p;
    };
    int*      cnt      = (int*)alloc(4ull * N_NODES);   // counts, then cursor
    int*      offs     = (int*)alloc(4ull * (N_NODES + 1));
    float*    dinv     = (float*)alloc(4ull * N_NODES);
    int*      bsum     = (int*)alloc(4ull * 128);
    uint2*    epk      = (uint2*)alloc(8ull * N_EDGES);          // packed CSR (8B)
    float*    stats    = (float*)alloc(4ull * 256);
    float*    ab       = (float*)alloc(4ull * 256);
    unsigned* sebf     = (unsigned*)alloc(4ull * N_NODES * 32);  // se bf16 (own buf!)
    unsigned* hb0      = (unsigned*)alloc(4ull * N_NODES * 32);  // bf16x2 packed
    unsigned* hb1      = (unsigned*)alloc(4ull * N_NODES * 32);
    unsigned* hb2      = (unsigned*)alloc(4ull * N_NODES * 32);
    unsigned* hb3      = (unsigned*)alloc(4ull * N_NODES * 32);
    unsigned* cbf      = (unsigned*)alloc(4ull * N_NODES * 16);  // c in bf16
    uint4*    bpkg     = (uint4*)alloc(16ull * 12 * C1);         // w_out1 B-frag order
    uint4*    bpkn     = (uint4*)alloc(16ull * 16 * HID);        // w_node B-frag order
    unsigned* hsbf     = (unsigned*)alloc(4ull * N_NODES * 32);  // hsum bf16

    hipMemsetAsync(cnt, 0, 4ull * N_NODES, stream);
    hipMemsetAsync(stats, 0, 4ull * 256, stream);

    k_count<<<(N_EDGES + 255) / 256, 256, 0, stream>>>(ei, cnt);
    k_scan1<<<SCAN_B, 1024, 0, stream>>>(cnt, offs, dinv, bsum);
    k_scan2<<<1, 1024, 0, stream>>>(bsum, SCAN_B);
    k_scan3<<<SCAN_B, 1024, 0, stream>>>(bsum, offs, cnt);   // cnt becomes cursor
    k_fill<<<(N_EDGES + 255) / 256, 256, 0, stream>>>(ei, cnt, dinv, epk);

    k_wpack<<<1, 256, 0, stream>>>(w_out1, w_node, bpkg, bpkn);
    k_convm<<<CONV_E_BLOCKS + CONV_C_BLOCKS, 256, 0, stream>>>(
        (const float4*)e, (uint4*)ebf, (const float4*)c, (uint2*)cbf);
    k_aggse<<<N_NODES / 16, 256, 0, stream>>>((const unsigned*)ebf, epk, offs, dinv,
                                              w_edge, b_edge, sebf);

    k_h0m<<<(ZSTRIPS + 3) / 4, 256, 0, stream>>>(x, bpkn, b_node, hb0);

    k_layer4<<<N_NODES * 16 / 256, 256, 0, stream>>>(hb0, sebf, epk, offs, dinv, hb1);
    k_layer4<<<N_NODES * 16 / 256, 256, 0, stream>>>(hb1, sebf, epk, offs, dinv, hb2);
    k_layer4s<<<N_NODES * 16 / 256, 256, 0, stream>>>(hb2, hb0, hb1, sebf, epk, offs,
                                                      dinv, hb3, hsbf);

    k_zmfma<<<(ZSTRIPS + 3) / 4, 256, 0, stream>>>(hsbf, cbf, bpkg, b_out1, zbf, stats);
    k_ab<<<1, 128, 0, stream>>>(stats, gamma, beta, ab);
    k_out4<<<(N_NODES * 4 + 255) / 256, 256, 0, stream>>>(zbf, ab, pa, w_out2, b_out2, out);
}

// Round 20
// 393.736 us; speedup vs baseline: 1.1657x; 1.1657x over previous
//
#include <hip/hip_runtime.h>
#include <math.h>

#define N_NODES 100000
#define N_EDGES 1000000
#define HID     64
#define HIER    32
#define NDIM    128
#define EDIM    32
#define K1      96    // HIER + HID
#define C1      128   // 2*HID
#define NCLS    10
#define BN_EPS  1e-5f
#define SCAN_B  98    // ceil(N_NODES/1024)
#define ZSTRIPS 6250  // N_NODES / 16
#define CONV_E_BLOCKS 15625   // 4M threads, 8 floats each
#define CONV_C_BLOCKS 3125    // N*8 float4s / 256

typedef __attribute__((ext_vector_type(8))) short short8;
typedef __attribute__((ext_vector_type(4))) float f32x4;

// pack two f32 -> (bf16(a) | bf16(b)<<16), round-to-nearest-even
__device__ __forceinline__ unsigned pk_bf16(float a, float b) {
    unsigned ua = __float_as_uint(a);
    ua = (ua + 0x7FFFu + ((ua >> 16) & 1u)) >> 16;
    unsigned ub = __float_as_uint(b);
    ub = (ub + 0x7FFFu + ((ub >> 16) & 1u)) & 0xFFFF0000u;
    return ua | ub;
}
__device__ __forceinline__ float bf_lo(unsigned g) { return __uint_as_float(g << 16); }
__device__ __forceinline__ float bf_hi(unsigned g) { return __uint_as_float(g & 0xFFFF0000u); }
__device__ __forceinline__ short8 as_s8(uint4 u) {
    union { uint4 u; short8 s; } c; c.u = u; return c.s;
}

// ---------------- CSR build ----------------

__global__ void k_count(const int* __restrict__ ei, int* __restrict__ cnt) {
    int i = blockIdx.x * blockDim.x + threadIdx.x;
    if (i < N_EDGES) atomicAdd(&cnt[ei[N_EDGES + i]], 1);
}

__global__ void k_scan1(const int* __restrict__ cnt, int* __restrict__ offs,
                        float* __restrict__ dinv, int* __restrict__ bsum) {
    __shared__ int buf[2][1024];
    int t = threadIdx.x, b = blockIdx.x;
    int i = b * 1024 + t;
    int v = (i < N_NODES) ? cnt[i] : 0;
    buf[0][t] = v; __syncthreads();
    int pi = 0;
    for (int off = 1; off < 1024; off <<= 1) {
        int x = buf[pi][t];
        if (t >= off) x += buf[pi][t - off];
        buf[pi ^ 1][t] = x; __syncthreads(); pi ^= 1;
    }
    int incl = buf[pi][t];
    if (i < N_NODES) {
        offs[i] = incl - v;
        dinv[i] = rsqrtf((float)(v + 1));
    }
    if (t == 1023) bsum[b] = incl;
}

__global__ void k_scan2(int* __restrict__ bsum, int nb) {
    __shared__ int buf[2][1024];
    int t = threadIdx.x;
    int v = (t < nb) ? bsum[t] : 0;
    buf[0][t] = v; __syncthreads();
    int pi = 0;
    for (int off = 1; off < 1024; off <<= 1) {
        int x = buf[pi][t];
        if (t >= off) x += buf[pi][t - off];
        buf[pi ^ 1][t] = x; __syncthreads(); pi ^= 1;
    }
    int incl = buf[pi][t];
    if (t < nb) bsum[t] = incl - v;
}

// also pre-initializes cursor = offs (k_fill then needs ONE random access/edge)
__global__ void k_scan3(const int* __restrict__ bsum, int* __restrict__ offs,
                        int* __restrict__ cursor) {
    int b = blockIdx.x;
    int i = b * 1024 + threadIdx.x;
    if (i < N_NODES) {
        int v = offs[i] + bsum[b];
        offs[i] = v;
        cursor[i] = v;
    }
    if (i == 0) offs[N_NODES] = N_EDGES;
}

// packed CSR record (8B): x = eid(20b) | src_low12 << 20 ; y = src_hi5 | norm_bf16 << 16
__global__ void k_fill(const int* __restrict__ ei, int* __restrict__ cursor,
                       const float* __restrict__ dinv, uint2* __restrict__ epk) {
    int i = blockIdx.x * blockDim.x + threadIdx.x;
    if (i >= N_EDGES) return;
    int s = ei[i], d = ei[N_EDGES + i];
    int pos = atomicAdd(&cursor[d], 1);
    unsigned nhi = pk_bf16(dinv[s], 0.f) << 16;
    epk[pos] = make_uint2((unsigned)i | ((unsigned)(s & 0xFFF) << 20),
                          nhi | (unsigned)(s >> 12));
}

// ---------------- merged streaming converts: e -> ebf, c -> cbf ----------------

__global__ __launch_bounds__(256) void k_convm(const float4* __restrict__ e4,
                                               uint4* __restrict__ eb4,
                                               const float4* __restrict__ c4,
                                               uint2* __restrict__ cb2) {
    int b = blockIdx.x;
    if (b < CONV_E_BLOCKS) {
        int i = b * 256 + threadIdx.x;
        float4 a = e4[(size_t)2 * i];
        float4 bb = e4[(size_t)2 * i + 1];
        uint4 pk;
        pk.x = pk_bf16(a.x, a.y); pk.y = pk_bf16(a.z, a.w);
        pk.z = pk_bf16(bb.x, bb.y); pk.w = pk_bf16(bb.z, bb.w);
        eb4[i] = pk;
    } else {
        int i = (b - CONV_E_BLOCKS) * 256 + threadIdx.x;
        if (i < N_NODES * 8) {
            float4 a = c4[i];
            cb2[i] = make_uint2(pk_bf16(a.x, a.y), pk_bf16(a.z, a.w));
        }
    }
}

// w1 [96][128] -> bpkg (12 groups x 128 cols); w_node [128][64] -> bpkn (16 x 64).
__global__ void k_wpack(const float* __restrict__ w1, const float* __restrict__ wn,
                        uint4* __restrict__ bpkg, uint4* __restrict__ bpkn) {
    for (int i = threadIdx.x; i < 12 * C1 + 16 * HID; i += 256) {
        if (i < 12 * C1) {
            int g = i >> 7, n = i & 127;
            uint4 r;
            r.x = pk_bf16(w1[(8 * g + 0) * C1 + n], w1[(8 * g + 1) * C1 + n]);
            r.y = pk_bf16(w1[(8 * g + 2) * C1 + n], w1[(8 * g + 3) * C1 + n]);
            r.z = pk_bf16(w1[(8 * g + 4) * C1 + n], w1[(8 * g + 5) * C1 + n]);
            r.w = pk_bf16(w1[(8 * g + 6) * C1 + n], w1[(8 * g + 7) * C1 + n]);
            bpkg[i] = r;
        } else {
            int j = i - 12 * C1;
            int g = j >> 6, n = j & 63;
            int kb = (g >> 2) * 32 + (g & 3) * 8;
            uint4 r;
            r.x = pk_bf16(wn[(kb + 0) * HID + n], wn[(kb + 1) * HID + n]);
            r.y = pk_bf16(wn[(kb + 2) * HID + n], wn[(kb + 3) * HID + n]);
            r.z = pk_bf16(wn[(kb + 4) * HID + n], wn[(kb + 5) * HID + n]);
            r.w = pk_bf16(wn[(kb + 6) * HID + n], wn[(kb + 7) * HID + n]);
            bpkn[j] = r;
        }
    }
}

// ---------------- fused edge aggregation + se ----------------
// Block = 16 nodes. Phase 1 (quarter-wave gather) -> agg rows in LDS.
// Phase 2: se = agg @ w_edge + wsum*b_edge in-block (w_edge in LDS),
// written packed bf16. NOTE: sebf must NOT alias ebf (reads are concurrent).

__global__ __launch_bounds__(256) void k_aggse(const unsigned* __restrict__ ebfu,
                                               const uint2* __restrict__ epk,
                                               const int* __restrict__ offs,
                                               const float* __restrict__ dinv,
                                               const float* __restrict__ we,
                                               const float* __restrict__ be,
                                               unsigned* __restrict__ sebf) {
    __shared__ float aggT[16][33];
    __shared__ float wsum[16];
    __shared__ float wes[EDIM * HID];   // 8 KB
    __shared__ float bes[HID];
    int tid = threadIdx.x;
    for (int i = tid; i < EDIM * HID; i += 256) wes[i] = we[i];
    if (tid < HID) bes[tid] = be[tid];
    int node = tid >> 4, q = tid & 15;
    int v = blockIdx.x * 16 + node;            // grid = 6250 -> always < N_NODES
    int start = offs[v], end = offs[v + 1];
    float ax = 0.f, ay = 0.f, wacc = 0.f;
    for (int i = start; i < end; i += 4) {
        int i1 = i + 1, i2 = i + 2, i3 = i + 3;
        uint2 p0 = epk[i];
        uint2 p1 = (i1 < end) ? epk[i1] : make_uint2(0u, 0u);
        uint2 p2 = (i2 < end) ? epk[i2] : make_uint2(0u, 0u);
        uint2 p3 = (i3 < end) ? epk[i3] : make_uint2(0u, 0u);
        float n0 = bf_hi(p0.y), n1 = bf_hi(p1.y);
        float n2 = bf_hi(p2.y), n3 = bf_hi(p3.y);
        unsigned g0 = ebfu[(size_t)(p0.x & 0xFFFFFu) * 16 + q];
        unsigned g1 = ebfu[(size_t)(p1.x & 0xFFFFFu) * 16 + q];
        unsigned g2 = ebfu[(size_t)(p2.x & 0xFFFFFu) * 16 + q];
        unsigned g3 = ebfu[(size_t)(p3.x & 0xFFFFFu) * 16 + q];
        ax += n0 * bf_lo(g0) + n1 * bf_lo(g1) + n2 * bf_lo(g2) + n3 * bf_lo(g3);
        ay += n0 * bf_hi(g0) + n1 * bf_hi(g1) + n2 * bf_hi(g2) + n3 * bf_hi(g3);
        wacc += n0 + n1 + n2 + n3;
    }
    float dv = dinv[v];
    aggT[node][2 * q]     = dv * ax;
    aggT[node][2 * q + 1] = dv * ay;
    if (q == 0) wsum[node] = dv * wacc;
    __syncthreads();
    // phase 2: this thread computes se outputs n0..n0+3 for its node
    int n0 = q * 4;
    float ws_ = wsum[node];
    float o0 = ws_ * bes[n0],     o1 = ws_ * bes[n0 + 1];
    float o2 = ws_ * bes[n0 + 2], o3 = ws_ * bes[n0 + 3];
    #pragma unroll
    for (int k = 0; k < EDIM; ++k) {
        float a = aggT[node][k];
        const float* wr = &wes[k * HID + n0];
        o0 += a * wr[0]; o1 += a * wr[1]; o2 += a * wr[2]; o3 += a * wr[3];
    }
    *(uint2*)&sebf[(size_t)v * 32 + q * 2] =
        make_uint2(pk_bf16(o0, o1), pk_bf16(o2, o3));
}

// ---------------- node encoder via MFMA: hb0 = bf16(x @ w_node + b) ----------------

__global__ __launch_bounds__(256) void k_h0m(const float* __restrict__ x,
                                             const uint4* __restrict__ bpkn,
                                             const float* __restrict__ bias,
                                             unsigned* __restrict__ hbf) {
    int tid = threadIdx.x;
    int wave = tid >> 6, lane = tid & 63;
    int l15 = lane & 15, lg = lane >> 4;
    int strip = blockIdx.x * 4 + wave;
    if (strip >= ZSTRIPS) return;
    int row = strip * 16 + l15;
    short8 A[4];
    #pragma unroll
    for (int kb = 0; kb < 4; ++kb) {
        const float4* xp = (const float4*)&x[(size_t)row * NDIM + kb * 32 + lg * 8];
        float4 a = xp[0], b = xp[1];
        uint4 u;
        u.x = pk_bf16(a.x, a.y); u.y = pk_bf16(a.z, a.w);
        u.z = pk_bf16(b.x, b.y); u.w = pk_bf16(b.z, b.w);
        A[kb] = as_s8(u);
    }
    int rb = strip * 16 + lg * 4;
    #pragma unroll
    for (int ct = 0; ct < 4; ++ct) {
        int n = ct * 16 + l15;
        f32x4 acc = {0.f, 0.f, 0.f, 0.f};
        #pragma unroll
        for (int kb = 0; kb < 4; ++kb) {
            short8 B = as_s8(bpkn[(kb * 4 + lg) * HID + n]);
            acc = __builtin_amdgcn_mfma_f32_16x16x32_bf16(A[kb], B, acc, 0, 0, 0);
        }
        float bn = bias[n];
        #pragma unroll
        for (int i = 0; i < 4; ++i) {
            float hv = acc[i] + bn;
            float ph = __shfl_xor(hv, 1);
            if ((l15 & 1) == 0)
                hbf[(size_t)(rb + i) * 32 + (n >> 1)] = pk_bf16(hv, ph);
        }
    }
}

// ---------------- GCN layer (quarter-wave: 4 nodes/wave, uint2 lanes, unroll 8) ----------------

__device__ __forceinline__ int dec_src(uint2 p) {
    return (int)(((p.y & 0xFFFFu) << 12) | (p.x >> 20));
}

__global__ __launch_bounds__(256) void k_layer4(const unsigned* __restrict__ hold,
                                                const unsigned* __restrict__ sebf,
                                                const uint2* __restrict__ epk,
                                                const int* __restrict__ offs,
                                                const float* __restrict__ dinv,
                                                unsigned* __restrict__ hnew) {
    int v = (blockIdx.x * 256 + threadIdx.x) >> 4;
    if (v >= N_NODES) return;
    int q = threadIdx.x & 15;                 // uint2 index: dims 4q..4q+3
    int start = offs[v], end = offs[v + 1];
    float dv = dinv[v];
    size_t vp = (size_t)v * 16 + q;
    uint2 hv = ((const uint2*)hold)[vp];
    float a0 = dv * bf_lo(hv.x), a1 = dv * bf_hi(hv.x);
    float a2 = dv * bf_lo(hv.y), a3 = dv * bf_hi(hv.y);
    for (int i = start; i < end; i += 8) {
        int idx[8]; float nn[8]; uint2 gg[8];
        #pragma unroll
        for (int u = 0; u < 8; ++u) {
            int ii = i + u;
            uint2 p = (ii < end) ? epk[ii] : make_uint2(0u, 0u);
            idx[u] = dec_src(p);
            nn[u]  = bf_hi(p.y);
        }
        #pragma unroll
        for (int u = 0; u < 8; ++u) gg[u] = ((const uint2*)hold)[(size_t)idx[u] * 16 + q];
        #pragma unroll
        for (int u = 0; u < 8; ++u) {
            a0 += nn[u] * bf_lo(gg[u].x); a1 += nn[u] * bf_hi(gg[u].x);
            a2 += nn[u] * bf_lo(gg[u].y); a3 += nn[u] * bf_hi(gg[u].y);
        }
    }
    uint2 sv = ((const uint2*)sebf)[vp];
    float r0 = bf_lo(sv.x) + dv * a0;
    float r1 = bf_hi(sv.x) + dv * a1;
    float r2 = bf_lo(sv.y) + dv * a2;
    float r3 = bf_hi(sv.y) + dv * a3;
    r0 = (r0 > 0.f) ? r0 : 0.2f * r0;
    r1 = (r1 > 0.f) ? r1 : 0.2f * r1;
    r2 = (r2 > 0.f) ? r2 : 0.2f * r2;
    r3 = (r3 > 0.f) ? r3 : 0.2f * r3;
    ((uint2*)hnew)[vp] = make_uint2(pk_bf16(r0, r1), pk_bf16(r2, r3));
}

// layer 3 variant: also emits hsbf = bf16(h0 + h1 + h2 + h3)
__global__ __launch_bounds__(256) void k_layer4s(const unsigned* __restrict__ hold, // = h2
                                                 const unsigned* __restrict__ hb0,
                                                 const unsigned* __restrict__ hb1,
                                                 const unsigned* __restrict__ sebf,
                                                 const uint2* __restrict__ epk,
                                                 const int* __restrict__ offs,
                                                 const float* __restrict__ dinv,
                                                 unsigned* __restrict__ hnew,
                                                 unsigned* __restrict__ hsbf) {
    int v = (blockIdx.x * 256 + threadIdx.x) >> 4;
    if (v >= N_NODES) return;
    int q = threadIdx.x & 15;
    int start = offs[v], end = offs[v + 1];
    float dv = dinv[v];
    size_t vp = (size_t)v * 16 + q;
    uint2 hv = ((const uint2*)hold)[vp];
    float a0 = dv * bf_lo(hv.x), a1 = dv * bf_hi(hv.x);
    float a2 = dv * bf_lo(hv.y), a3 = dv * bf_hi(hv.y);
    for (int i = start; i < end; i += 8) {
        int idx[8]; float nn[8]; uint2 gg[8];
        #pragma unroll
        for (int u = 0; u < 8; ++u) {
            int ii = i + u;
            uint2 p = (ii < end) ? epk[ii] : make_uint2(0u, 0u);
            idx[u] = dec_src(p);
            nn[u]  = bf_hi(p.y);
        }
        #pragma unroll
        for (int u = 0; u < 8; ++u) gg[u] = ((const uint2*)hold)[(size_t)idx[u] * 16 + q];
        #pragma unroll
        for (int u = 0; u < 8; ++u) {
            a0 += nn[u] * bf_lo(gg[u].x); a1 += nn[u] * bf_hi(gg[u].x);
            a2 += nn[u] * bf_lo(gg[u].y); a3 += nn[u] * bf_hi(gg[u].y);
        }
    }
    uint2 sv = ((const uint2*)sebf)[vp];
    float r0 = bf_lo(sv.x) + dv * a0;
    float r1 = bf_hi(sv.x) + dv * a1;
    float r2 = bf_lo(sv.y) + dv * a2;
    float r3 = bf_hi(sv.y) + dv * a3;
    r0 = (r0 > 0.f) ? r0 : 0.2f * r0;
    r1 = (r1 > 0.f) ? r1 : 0.2f * r1;
    r2 = (r2 > 0.f) ? r2 : 0.2f * r2;
    r3 = (r3 > 0.f) ? r3 : 0.2f * r3;
    ((uint2*)hnew)[vp] = make_uint2(pk_bf16(r0, r1), pk_bf16(r2, r3));
    uint2 g0 = ((const uint2*)hb0)[vp];
    uint2 g1 = ((const uint2*)hb1)[vp];
    float s0 = r0 + bf_lo(g0.x) + bf_lo(g1.x) + bf_lo(hv.x);
    float s1 = r1 + bf_hi(g0.x) + bf_hi(g1.x) + bf_hi(hv.x);
    float s2 = r2 + bf_lo(g0.y) + bf_lo(g1.y) + bf_lo(hv.y);
    float s3 = r3 + bf_hi(g0.y) + bf_hi(g1.y) + bf_hi(hv.y);
    ((uint2*)hsbf)[vp] = make_uint2(pk_bf16(s0, s1), pk_bf16(s2, s3));
}

// ---------------- z GEMM + BN stats via MFMA (verified R15) ----------------

__global__ __launch_bounds__(256) void k_zmfma(const unsigned* __restrict__ hsbf,
                                               const unsigned* __restrict__ cbf,
                                               const uint4* __restrict__ bpkg,
                                               const float* __restrict__ b1,
                                               unsigned* __restrict__ zbf,
                                               float* __restrict__ stats) {
    __shared__ float red[2][4][C1];   // 4 KB
    int tid = threadIdx.x;
    int wave = tid >> 6, lane = tid & 63;
    int l15 = lane & 15, lg = lane >> 4;
    int strip = blockIdx.x * 4 + wave;
    float sN[8], qN[8];
    #pragma unroll
    for (int j = 0; j < 8; ++j) { sN[j] = 0.f; qN[j] = 0.f; }
    if (strip < ZSTRIPS) {
        int row = strip * 16 + l15;
        short8 A0 = as_s8(*(const uint4*)&hsbf[(size_t)row * 32 + lg * 4]);       // k 0..31
        short8 A1 = as_s8(*(const uint4*)&hsbf[(size_t)row * 32 + 16 + lg * 4]);  // k 32..63
        short8 A2 = as_s8(*(const uint4*)&cbf[(size_t)row * 16 + lg * 4]);        // k 64..95
        int rb = strip * 16 + lg * 4;
        #pragma unroll
        for (int ct = 0; ct < 8; ++ct) {
            int n = ct * 16 + l15;
            short8 B0 = as_s8(bpkg[lg * C1 + n]);
            short8 B1 = as_s8(bpkg[(4 + lg) * C1 + n]);
            short8 B2 = as_s8(bpkg[(8 + lg) * C1 + n]);
            f32x4 acc = {0.f, 0.f, 0.f, 0.f};
            acc = __builtin_amdgcn_mfma_f32_16x16x32_bf16(A0, B0, acc, 0, 0, 0);
            acc = __builtin_amdgcn_mfma_f32_16x16x32_bf16(A1, B1, acc, 0, 0, 0);
            acc = __builtin_amdgcn_mfma_f32_16x16x32_bf16(A2, B2, acc, 0, 0, 0);
            float bias = b1[n];
            #pragma unroll
            for (int i = 0; i < 4; ++i) {
                float zz = acc[i] + bias;
                sN[ct] += zz; qN[ct] += zz * zz;
                float pz = __shfl_xor(zz, 1);
                if ((l15 & 1) == 0)
                    zbf[(size_t)(rb + i) * 64 + (n >> 1)] = pk_bf16(zz, pz);
            }
        }
    }
    #pragma unroll
    for (int j = 0; j < 8; ++j) {
        sN[j] += __shfl_xor(sN[j], 16); sN[j] += __shfl_xor(sN[j], 32);
        qN[j] += __shfl_xor(qN[j], 16); qN[j] += __shfl_xor(qN[j], 32);
    }
    if (lane < 16) {
        #pragma unroll
        for (int ct = 0; ct < 8; ++ct) {
            red[0][wave][ct * 16 + lane] = sN[ct];
            red[1][wave][ct * 16 + lane] = qN[ct];
        }
    }
    __syncthreads();
    if (tid < C1) {
        atomicAdd(&stats[tid],
                  red[0][0][tid] + red[0][1][tid] + red[0][2][tid] + red[0][3][tid]);
        atomicAdd(&stats[C1 + tid],
                  red[1][0][tid] + red[1][1][tid] + red[1][2][tid] + red[1][3][tid]);
    }
}

__global__ void k_ab(const float* __restrict__ stats, const float* __restrict__ gamma,
                     const float* __restrict__ beta, float* __restrict__ ab) {
    int t = threadIdx.x;
    if (t < C1) {
        float mu = stats[t] / (float)N_NODES;
        float var = stats[C1 + t] / (float)N_NODES - mu * mu;
        float inv = rsqrtf(var + BN_EPS);
        float a = gamma[t] * inv;
        ab[t] = a;
        ab[C1 + t] = beta[t] - mu * a;
    }
}

// ---------------- output: thread-per-node, wave-uniform scalar weights ----------------
// (k_out4's per-lane d0 broke the s_load broadcast -> 90us. Reverted to this.)

__global__ __launch_bounds__(256) void k_out3(const unsigned* __restrict__ zbf,
                                              const float* __restrict__ ab,
                                              const float* __restrict__ pa,
                                              const float* __restrict__ w2,
                                              const float* __restrict__ b2,
                                              float* __restrict__ out) {
    int v = blockIdx.x * 256 + threadIdx.x;
    if (v >= N_NODES) return;
    float alpha = pa[0];
    float acc[NCLS];
    #pragma unroll
    for (int j = 0; j < NCLS; ++j) acc[j] = b2[j];
    const uint4* zr = (const uint4*)(zbf + (size_t)v * 64);
    #pragma unroll
    for (int pk4 = 0; pk4 < 16; ++pk4) {
        uint4 g = zr[pk4];
        unsigned gw[4] = {g.x, g.y, g.z, g.w};
        #pragma unroll
        for (int w = 0; w < 4; ++w) {
            int d0 = pk4 * 8 + w * 2;
            float p0 = bf_lo(gw[w]) * ab[d0]     + ab[C1 + d0];
            float p1 = bf_hi(gw[w]) * ab[d0 + 1] + ab[C1 + d0 + 1];
            p0 = (p0 > 0.f) ? p0 : alpha * p0;
            p1 = (p1 > 0.f) ? p1 : alpha * p1;
            #pragma unroll
            for (int j = 0; j < NCLS; ++j)
                acc[j] += p0 * w2[d0 * NCLS + j] + p1 * w2[(d0 + 1) * NCLS + j];
        }
    }
    #pragma unroll
    for (int j = 0; j < NCLS; ++j) out[(size_t)v * NCLS + j] = acc[j];
}

// ---------------- host ----------------

extern "C" void kernel_launch(void* const* d_in, const int* in_sizes, int n_in,
                              void* d_out, int out_size, void* d_ws, size_t ws_size,
                              hipStream_t stream) {
    const float* x      = (const float*)d_in[0];
    const float* e      = (const float*)d_in[1];
    const float* c      = (const float*)d_in[2];
    const float* w_node = (const float*)d_in[3];
    const float* b_node = (const float*)d_in[4];
    const float* w_edge = (const float*)d_in[5];
    const float* b_edge = (const float*)d_in[6];
    const float* w_out1 = (const float*)d_in[7];
    const float* b_out1 = (const float*)d_in[8];
    const float* gamma  = (const float*)d_in[9];
    const float* beta   = (const float*)d_in[10];
    const float* pa     = (const float*)d_in[11];
    const float* w_out2 = (const float*)d_in[12];
    const float* b_out2 = (const float*)d_in[13];
    const int*   ei     = (const int*)d_in[14];
    float* out = (float*)d_out;

    char* wsb = (char*)d_ws;
    // Region A (64MB): ebf [bf16 1M x 32] eid order; LIVE until k_aggse completes.
    //   zbf (25.6MB) overlays region A at offset 0 (written in k_zmfma, after
    //   ebf is dead). sebf has its OWN allocation (concurrent with live ebf).
    ushort*   ebf  = (ushort*)wsb;
    unsigned* zbf  = (unsigned*)wsb;
    size_t off = (64000000 + 255) & ~(size_t)255;
    auto alloc = [&](size_t bytes) {
        void* p = wsb + off;
        off = (off + bytes + 255) & ~(size_t)255;
        return p;
    };
    int*      cnt      = (int*)alloc(4ull * N_NODES);   // counts, then cursor
    int*      offs     = (int*)alloc(4ull * (N_NODES + 1));
    float*    dinv     = (float*)alloc(4ull * N_NODES);
    int*      bsum     = (int*)alloc(4ull * 128);
    uint2*    epk      = (uint2*)alloc(8ull * N_EDGES);          // packed CSR (8B)
    float*    stats    = (float*)alloc(4ull * 256);
    float*    ab       = (float*)alloc(4ull * 256);
    unsigned* sebf     = (unsigned*)alloc(4ull * N_NODES * 32);  // se bf16 (own buf!)
    unsigned* hb0      = (unsigned*)alloc(4ull * N_NODES * 32);  // bf16x2 packed
    unsigned* hb1      = (unsigned*)alloc(4ull * N_NODES * 32);
    unsigned* hb2      = (unsigned*)alloc(4ull * N_NODES * 32);
    unsigned* hb3      = (unsigned*)alloc(4ull * N_NODES * 32);
    unsigned* cbf      = (unsigned*)alloc(4ull * N_NODES * 16);  // c in bf16
    uint4*    bpkg     = (uint4*)alloc(16ull * 12 * C1);         // w_out1 B-frag order
    uint4*    bpkn     = (uint4*)alloc(16ull * 16 * HID);        // w_node B-frag order
    unsigned* hsbf     = (unsigned*)alloc(4ull * N_NODES * 32);  // hsum bf16

    hipMemsetAsync(cnt, 0, 4ull * N_NODES, stream);
    hipMemsetAsync(stats, 0, 4ull * 256, stream);

    k_count<<<(N_EDGES + 255) / 256, 256, 0, stream>>>(ei, cnt);
    k_scan1<<<SCAN_B, 1024, 0, stream>>>(cnt, offs, dinv, bsum);
    k_scan2<<<1, 1024, 0, stream>>>(bsum, SCAN_B);
    k_scan3<<<SCAN_B, 1024, 0, stream>>>(bsum, offs, cnt);   // cnt becomes cursor
    k_fill<<<(N_EDGES + 255) / 256, 256, 0, stream>>>(ei, cnt, dinv, epk);

    k_wpack<<<1, 256, 0, stream>>>(w_out1, w_node, bpkg, bpkn);
    k_convm<<<CONV_E_BLOCKS + CONV_C_BLOCKS, 256, 0, stream>>>(
        (const float4*)e, (uint4*)ebf, (const float4*)c, (uint2*)cbf);
    k_aggse<<<N_NODES / 16, 256, 0, stream>>>((const unsigned*)ebf, epk, offs, dinv,
                                              w_edge, b_edge, sebf);

    k_h0m<<<(ZSTRIPS + 3) / 4, 256, 0, stream>>>(x, bpkn, b_node, hb0);

    k_layer4<<<N_NODES * 16 / 256, 256, 0, stream>>>(hb0, sebf, epk, offs, dinv, hb1);
    k_layer4<<<N_NODES * 16 / 256, 256, 0, stream>>>(hb1, sebf, epk, offs, dinv, hb2);
    k_layer4s<<<N_NODES * 16 / 256, 256, 0, stream>>>(hb2, hb0, hb1, sebf, epk, offs,
                                                      dinv, hb3, hsbf);

    k_zmfma<<<(ZSTRIPS + 3) / 4, 256, 0, stream>>>(hsbf, cbf, bpkg, b_out1, zbf, stats);
    k_ab<<<1, 128, 0, stream>>>(stats, gamma, beta, ab);
    k_out3<<<(N_NODES + 255) / 256, 256, 0, stream>>>(zbf, ab, pa, w_out2, b_out2, out);
}

// Round 21
// 393.104 us; speedup vs baseline: 1.1675x; 1.0016x over previous
//
#include <hip/hip_runtime.h>
#include <math.h>

#define N_NODES 100000
#define N_EDGES 1000000
#define HID     64
#define HIER    32
#define NDIM    128
#define EDIM    32
#define K1      96    // HIER + HID
#define C1      128   // 2*HID
#define NCLS    10
#define BN_EPS  1e-5f
#define SCAN_B  98    // ceil(N_NODES/1024)
#define ZSTRIPS 6250  // N_NODES / 16
#define CONV_E_BLOCKS 15625   // 4M threads, 8 floats each
#define CONV_C_BLOCKS 3125    // N*8 float4s / 256

typedef __attribute__((ext_vector_type(8))) short short8;
typedef __attribute__((ext_vector_type(4))) float f32x4;

// pack two f32 -> (bf16(a) | bf16(b)<<16), round-to-nearest-even
__device__ __forceinline__ unsigned pk_bf16(float a, float b) {
    unsigned ua = __float_as_uint(a);
    ua = (ua + 0x7FFFu + ((ua >> 16) & 1u)) >> 16;
    unsigned ub = __float_as_uint(b);
    ub = (ub + 0x7FFFu + ((ub >> 16) & 1u)) & 0xFFFF0000u;
    return ua | ub;
}
__device__ __forceinline__ float bf_lo(unsigned g) { return __uint_as_float(g << 16); }
__device__ __forceinline__ float bf_hi(unsigned g) { return __uint_as_float(g & 0xFFFF0000u); }
__device__ __forceinline__ short8 as_s8(uint4 u) {
    union { uint4 u; short8 s; } c; c.u = u; return c.s;
}

// ---------------- CSR build ----------------

__global__ void k_count(const int* __restrict__ ei, int* __restrict__ cnt) {
    int i = blockIdx.x * blockDim.x + threadIdx.x;
    if (i < N_EDGES) atomicAdd(&cnt[ei[N_EDGES + i]], 1);
}

__global__ void k_scan1(const int* __restrict__ cnt, int* __restrict__ offs,
                        float* __restrict__ dinv, int* __restrict__ bsum) {
    __shared__ int buf[2][1024];
    int t = threadIdx.x, b = blockIdx.x;
    int i = b * 1024 + t;
    int v = (i < N_NODES) ? cnt[i] : 0;
    buf[0][t] = v; __syncthreads();
    int pi = 0;
    for (int off = 1; off < 1024; off <<= 1) {
        int x = buf[pi][t];
        if (t >= off) x += buf[pi][t - off];
        buf[pi ^ 1][t] = x; __syncthreads(); pi ^= 1;
    }
    int incl = buf[pi][t];
    if (i < N_NODES) {
        offs[i] = incl - v;
        dinv[i] = rsqrtf((float)(v + 1));
    }
    if (t == 1023) bsum[b] = incl;
}

__global__ void k_scan2(int* __restrict__ bsum, int nb) {
    __shared__ int buf[2][1024];
    int t = threadIdx.x;
    int v = (t < nb) ? bsum[t] : 0;
    buf[0][t] = v; __syncthreads();
    int pi = 0;
    for (int off = 1; off < 1024; off <<= 1) {
        int x = buf[pi][t];
        if (t >= off) x += buf[pi][t - off];
        buf[pi ^ 1][t] = x; __syncthreads(); pi ^= 1;
    }
    int incl = buf[pi][t];
    if (t < nb) bsum[t] = incl - v;
}

// also pre-initializes cursor = offs (k_fill then needs ONE random access/edge)
__global__ void k_scan3(const int* __restrict__ bsum, int* __restrict__ offs,
                        int* __restrict__ cursor) {
    int b = blockIdx.x;
    int i = b * 1024 + threadIdx.x;
    if (i < N_NODES) {
        int v = offs[i] + bsum[b];
        offs[i] = v;
        cursor[i] = v;
    }
    if (i == 0) offs[N_NODES] = N_EDGES;
}

// packed CSR record (8B): x = eid(20b) | src_low12 << 20 ; y = src_hi5 | norm_bf16 << 16
__global__ void k_fill(const int* __restrict__ ei, int* __restrict__ cursor,
                       const float* __restrict__ dinv, uint2* __restrict__ epk) {
    int i = blockIdx.x * blockDim.x + threadIdx.x;
    if (i >= N_EDGES) return;
    int s = ei[i], d = ei[N_EDGES + i];
    int pos = atomicAdd(&cursor[d], 1);
    unsigned nhi = pk_bf16(dinv[s], 0.f) << 16;
    epk[pos] = make_uint2((unsigned)i | ((unsigned)(s & 0xFFF) << 20),
                          nhi | (unsigned)(s >> 12));
}

// ---------------- merged streaming converts: e -> ebf, c -> cbf ----------------

__global__ __launch_bounds__(256) void k_convm(const float4* __restrict__ e4,
                                               uint4* __restrict__ eb4,
                                               const float4* __restrict__ c4,
                                               uint2* __restrict__ cb2) {
    int b = blockIdx.x;
    if (b < CONV_E_BLOCKS) {
        int i = b * 256 + threadIdx.x;
        float4 a = e4[(size_t)2 * i];
        float4 bb = e4[(size_t)2 * i + 1];
        uint4 pk;
        pk.x = pk_bf16(a.x, a.y); pk.y = pk_bf16(a.z, a.w);
        pk.z = pk_bf16(bb.x, bb.y); pk.w = pk_bf16(bb.z, bb.w);
        eb4[i] = pk;
    } else {
        int i = (b - CONV_E_BLOCKS) * 256 + threadIdx.x;
        if (i < N_NODES * 8) {
            float4 a = c4[i];
            cb2[i] = make_uint2(pk_bf16(a.x, a.y), pk_bf16(a.z, a.w));
        }
    }
}

// w1 [96][128] -> bpkg (12 groups x 128 cols); w_node [128][64] -> bpkn (16 x 64).
__global__ void k_wpack(const float* __restrict__ w1, const float* __restrict__ wn,
                        uint4* __restrict__ bpkg, uint4* __restrict__ bpkn) {
    for (int i = threadIdx.x; i < 12 * C1 + 16 * HID; i += 256) {
        if (i < 12 * C1) {
            int g = i >> 7, n = i & 127;
            uint4 r;
            r.x = pk_bf16(w1[(8 * g + 0) * C1 + n], w1[(8 * g + 1) * C1 + n]);
            r.y = pk_bf16(w1[(8 * g + 2) * C1 + n], w1[(8 * g + 3) * C1 + n]);
            r.z = pk_bf16(w1[(8 * g + 4) * C1 + n], w1[(8 * g + 5) * C1 + n]);
            r.w = pk_bf16(w1[(8 * g + 6) * C1 + n], w1[(8 * g + 7) * C1 + n]);
            bpkg[i] = r;
        } else {
            int j = i - 12 * C1;
            int g = j >> 6, n = j & 63;
            int kb = (g >> 2) * 32 + (g & 3) * 8;
            uint4 r;
            r.x = pk_bf16(wn[(kb + 0) * HID + n], wn[(kb + 1) * HID + n]);
            r.y = pk_bf16(wn[(kb + 2) * HID + n], wn[(kb + 3) * HID + n]);
            r.z = pk_bf16(wn[(kb + 4) * HID + n], wn[(kb + 5) * HID + n]);
            r.w = pk_bf16(wn[(kb + 6) * HID + n], wn[(kb + 7) * HID + n]);
            bpkn[j] = r;
        }
    }
}

// ---------------- fused edge aggregation + se ----------------
// Block = 16 nodes. Phase 1 (quarter-wave gather) -> agg rows in LDS.
// Phase 2: se = agg @ w_edge + wsum*b_edge in-block (w_edge in LDS),
// written packed bf16. NOTE: sebf must NOT alias ebf (reads are concurrent).

__global__ __launch_bounds__(256) void k_aggse(const unsigned* __restrict__ ebfu,
                                               const uint2* __restrict__ epk,
                                               const int* __restrict__ offs,
                                               const float* __restrict__ dinv,
                                               const float* __restrict__ we,
                                               const float* __restrict__ be,
                                               unsigned* __restrict__ sebf) {
    __shared__ float aggT[16][33];
    __shared__ float wsum[16];
    __shared__ float wes[EDIM * HID];   // 8 KB
    __shared__ float bes[HID];
    int tid = threadIdx.x;
    for (int i = tid; i < EDIM * HID; i += 256) wes[i] = we[i];
    if (tid < HID) bes[tid] = be[tid];
    int node = tid >> 4, q = tid & 15;
    int v = blockIdx.x * 16 + node;            // grid = 6250 -> always < N_NODES
    int start = offs[v], end = offs[v + 1];
    float ax = 0.f, ay = 0.f, wacc = 0.f;
    for (int i = start; i < end; i += 4) {
        int i1 = i + 1, i2 = i + 2, i3 = i + 3;
        uint2 p0 = epk[i];
        uint2 p1 = (i1 < end) ? epk[i1] : make_uint2(0u, 0u);
        uint2 p2 = (i2 < end) ? epk[i2] : make_uint2(0u, 0u);
        uint2 p3 = (i3 < end) ? epk[i3] : make_uint2(0u, 0u);
        float n0 = bf_hi(p0.y), n1 = bf_hi(p1.y);
        float n2 = bf_hi(p2.y), n3 = bf_hi(p3.y);
        unsigned g0 = ebfu[(size_t)(p0.x & 0xFFFFFu) * 16 + q];
        unsigned g1 = ebfu[(size_t)(p1.x & 0xFFFFFu) * 16 + q];
        unsigned g2 = ebfu[(size_t)(p2.x & 0xFFFFFu) * 16 + q];
        unsigned g3 = ebfu[(size_t)(p3.x & 0xFFFFFu) * 16 + q];
        ax += n0 * bf_lo(g0) + n1 * bf_lo(g1) + n2 * bf_lo(g2) + n3 * bf_lo(g3);
        ay += n0 * bf_hi(g0) + n1 * bf_hi(g1) + n2 * bf_hi(g2) + n3 * bf_hi(g3);
        wacc += n0 + n1 + n2 + n3;
    }
    float dv = dinv[v];
    aggT[node][2 * q]     = dv * ax;
    aggT[node][2 * q + 1] = dv * ay;
    if (q == 0) wsum[node] = dv * wacc;
    __syncthreads();
    // phase 2: this thread computes se outputs n0..n0+3 for its node
    int n0 = q * 4;
    float ws_ = wsum[node];
    float o0 = ws_ * bes[n0],     o1 = ws_ * bes[n0 + 1];
    float o2 = ws_ * bes[n0 + 2], o3 = ws_ * bes[n0 + 3];
    #pragma unroll
    for (int k = 0; k < EDIM; ++k) {
        float a = aggT[node][k];
        const float* wr = &wes[k * HID + n0];
        o0 += a * wr[0]; o1 += a * wr[1]; o2 += a * wr[2]; o3 += a * wr[3];
    }
    *(uint2*)&sebf[(size_t)v * 32 + q * 2] =
        make_uint2(pk_bf16(o0, o1), pk_bf16(o2, o3));
}

// ---------------- node encoder via MFMA: hb0 = bf16(x @ w_node + b) ----------------

__global__ __launch_bounds__(256) void k_h0m(const float* __restrict__ x,
                                             const uint4* __restrict__ bpkn,
                                             const float* __restrict__ bias,
                                             unsigned* __restrict__ hbf) {
    int tid = threadIdx.x;
    int wave = tid >> 6, lane = tid & 63;
    int l15 = lane & 15, lg = lane >> 4;
    int strip = blockIdx.x * 4 + wave;
    if (strip >= ZSTRIPS) return;
    int row = strip * 16 + l15;
    short8 A[4];
    #pragma unroll
    for (int kb = 0; kb < 4; ++kb) {
        const float4* xp = (const float4*)&x[(size_t)row * NDIM + kb * 32 + lg * 8];
        float4 a = xp[0], b = xp[1];
        uint4 u;
        u.x = pk_bf16(a.x, a.y); u.y = pk_bf16(a.z, a.w);
        u.z = pk_bf16(b.x, b.y); u.w = pk_bf16(b.z, b.w);
        A[kb] = as_s8(u);
    }
    int rb = strip * 16 + lg * 4;
    #pragma unroll
    for (int ct = 0; ct < 4; ++ct) {
        int n = ct * 16 + l15;
        f32x4 acc = {0.f, 0.f, 0.f, 0.f};
        #pragma unroll
        for (int kb = 0; kb < 4; ++kb) {
            short8 B = as_s8(bpkn[(kb * 4 + lg) * HID + n]);
            acc = __builtin_amdgcn_mfma_f32_16x16x32_bf16(A[kb], B, acc, 0, 0, 0);
        }
        float bn = bias[n];
        #pragma unroll
        for (int i = 0; i < 4; ++i) {
            float hv = acc[i] + bn;
            float ph = __shfl_xor(hv, 1);
            if ((l15 & 1) == 0)
                hbf[(size_t)(rb + i) * 32 + (n >> 1)] = pk_bf16(hv, ph);
        }
    }
}

// ---------------- GCN layer (quarter-wave: 4 nodes/wave, uint2 lanes, unroll 8) ----------------

__device__ __forceinline__ int dec_src(uint2 p) {
    return (int)(((p.y & 0xFFFFu) << 12) | (p.x >> 20));
}

__global__ __launch_bounds__(256) void k_layer4(const unsigned* __restrict__ hold,
                                                const unsigned* __restrict__ sebf,
                                                const uint2* __restrict__ epk,
                                                const int* __restrict__ offs,
                                                const float* __restrict__ dinv,
                                                unsigned* __restrict__ hnew) {
    int v = (blockIdx.x * 256 + threadIdx.x) >> 4;
    if (v >= N_NODES) return;
    int q = threadIdx.x & 15;                 // uint2 index: dims 4q..4q+3
    int start = offs[v], end = offs[v + 1];
    float dv = dinv[v];
    size_t vp = (size_t)v * 16 + q;
    uint2 hv = ((const uint2*)hold)[vp];
    float a0 = dv * bf_lo(hv.x), a1 = dv * bf_hi(hv.x);
    float a2 = dv * bf_lo(hv.y), a3 = dv * bf_hi(hv.y);
    for (int i = start; i < end; i += 8) {
        int idx[8]; float nn[8]; uint2 gg[8];
        #pragma unroll
        for (int u = 0; u < 8; ++u) {
            int ii = i + u;
            uint2 p = (ii < end) ? epk[ii] : make_uint2(0u, 0u);
            idx[u] = dec_src(p);
            nn[u]  = bf_hi(p.y);
        }
        #pragma unroll
        for (int u = 0; u < 8; ++u) gg[u] = ((const uint2*)hold)[(size_t)idx[u] * 16 + q];
        #pragma unroll
        for (int u = 0; u < 8; ++u) {
            a0 += nn[u] * bf_lo(gg[u].x); a1 += nn[u] * bf_hi(gg[u].x);
            a2 += nn[u] * bf_lo(gg[u].y); a3 += nn[u] * bf_hi(gg[u].y);
        }
    }
    uint2 sv = ((const uint2*)sebf)[vp];
    float r0 = bf_lo(sv.x) + dv * a0;
    float r1 = bf_hi(sv.x) + dv * a1;
    float r2 = bf_lo(sv.y) + dv * a2;
    float r3 = bf_hi(sv.y) + dv * a3;
    r0 = (r0 > 0.f) ? r0 : 0.2f * r0;
    r1 = (r1 > 0.f) ? r1 : 0.2f * r1;
    r2 = (r2 > 0.f) ? r2 : 0.2f * r2;
    r3 = (r3 > 0.f) ? r3 : 0.2f * r3;
    ((uint2*)hnew)[vp] = make_uint2(pk_bf16(r0, r1), pk_bf16(r2, r3));
}

// layer 3 variant: also emits hsbf = bf16(h0 + h1 + h2 + h3)
__global__ __launch_bounds__(256) void k_layer4s(const unsigned* __restrict__ hold, // = h2
                                                 const unsigned* __restrict__ hb0,
                                                 const unsigned* __restrict__ hb1,
                                                 const unsigned* __restrict__ sebf,
                                                 const uint2* __restrict__ epk,
                                                 const int* __restrict__ offs,
                                                 const float* __restrict__ dinv,
                                                 unsigned* __restrict__ hnew,
                                                 unsigned* __restrict__ hsbf) {
    int v = (blockIdx.x * 256 + threadIdx.x) >> 4;
    if (v >= N_NODES) return;
    int q = threadIdx.x & 15;
    int start = offs[v], end = offs[v + 1];
    float dv = dinv[v];
    size_t vp = (size_t)v * 16 + q;
    uint2 hv = ((const uint2*)hold)[vp];
    float a0 = dv * bf_lo(hv.x), a1 = dv * bf_hi(hv.x);
    float a2 = dv * bf_lo(hv.y), a3 = dv * bf_hi(hv.y);
    for (int i = start; i < end; i += 8) {
        int idx[8]; float nn[8]; uint2 gg[8];
        #pragma unroll
        for (int u = 0; u < 8; ++u) {
            int ii = i + u;
            uint2 p = (ii < end) ? epk[ii] : make_uint2(0u, 0u);
            idx[u] = dec_src(p);
            nn[u]  = bf_hi(p.y);
        }
        #pragma unroll
        for (int u = 0; u < 8; ++u) gg[u] = ((const uint2*)hold)[(size_t)idx[u] * 16 + q];
        #pragma unroll
        for (int u = 0; u < 8; ++u) {
            a0 += nn[u] * bf_lo(gg[u].x); a1 += nn[u] * bf_hi(gg[u].x);
            a2 += nn[u] * bf_lo(gg[u].y); a3 += nn[u] * bf_hi(gg[u].y);
        }
    }
    uint2 sv = ((const uint2*)sebf)[vp];
    float r0 = bf_lo(sv.x) + dv * a0;
    float r1 = bf_hi(sv.x) + dv * a1;
    float r2 = bf_lo(sv.y) + dv * a2;
    float r3 = bf_hi(sv.y) + dv * a3;
    r0 = (r0 > 0.f) ? r0 : 0.2f * r0;
    r1 = (r1 > 0.f) ? r1 : 0.2f * r1;
    r2 = (r2 > 0.f) ? r2 : 0.2f * r2;
    r3 = (r3 > 0.f) ? r3 : 0.2f * r3;
    ((uint2*)hnew)[vp] = make_uint2(pk_bf16(r0, r1), pk_bf16(r2, r3));
    uint2 g0 = ((const uint2*)hb0)[vp];
    uint2 g1 = ((const uint2*)hb1)[vp];
    float s0 = r0 + bf_lo(g0.x) + bf_lo(g1.x) + bf_lo(hv.x);
    float s1 = r1 + bf_hi(g0.x) + bf_hi(g1.x) + bf_hi(hv.x);
    float s2 = r2 + bf_lo(g0.y) + bf_lo(g1.y) + bf_lo(hv.y);
    float s3 = r3 + bf_hi(g0.y) + bf_hi(g1.y) + bf_hi(hv.y);
    ((uint2*)hsbf)[vp] = make_uint2(pk_bf16(s0, s1), pk_bf16(s2, s3));
}

// ---------------- z GEMM + BN stats via MFMA (verified R15) ----------------

__global__ __launch_bounds__(256) void k_zmfma(const unsigned* __restrict__ hsbf,
                                               const unsigned* __restrict__ cbf,
                                               const uint4* __restrict__ bpkg,
                                               const float* __restrict__ b1,
                                               unsigned* __restrict__ zbf,
                                               float* __restrict__ stats) {
    __shared__ float red[2][4][C1];   // 4 KB
    int tid = threadIdx.x;
    int wave = tid >> 6, lane = tid & 63;
    int l15 = lane & 15, lg = lane >> 4;
    int strip = blockIdx.x * 4 + wave;
    float sN[8], qN[8];
    #pragma unroll
    for (int j = 0; j < 8; ++j) { sN[j] = 0.f; qN[j] = 0.f; }
    if (strip < ZSTRIPS) {
        int row = strip * 16 + l15;
        short8 A0 = as_s8(*(const uint4*)&hsbf[(size_t)row * 32 + lg * 4]);       // k 0..31
        short8 A1 = as_s8(*(const uint4*)&hsbf[(size_t)row * 32 + 16 + lg * 4]);  // k 32..63
        short8 A2 = as_s8(*(const uint4*)&cbf[(size_t)row * 16 + lg * 4]);        // k 64..95
        int rb = strip * 16 + lg * 4;
        #pragma unroll
        for (int ct = 0; ct < 8; ++ct) {
            int n = ct * 16 + l15;
            short8 B0 = as_s8(bpkg[lg * C1 + n]);
            short8 B1 = as_s8(bpkg[(4 + lg) * C1 + n]);
            short8 B2 = as_s8(bpkg[(8 + lg) * C1 + n]);
            f32x4 acc = {0.f, 0.f, 0.f, 0.f};
            acc = __builtin_amdgcn_mfma_f32_16x16x32_bf16(A0, B0, acc, 0, 0, 0);
            acc = __builtin_amdgcn_mfma_f32_16x16x32_bf16(A1, B1, acc, 0, 0, 0);
            acc = __builtin_amdgcn_mfma_f32_16x16x32_bf16(A2, B2, acc, 0, 0, 0);
            float bias = b1[n];
            #pragma unroll
            for (int i = 0; i < 4; ++i) {
                float zz = acc[i] + bias;
                sN[ct] += zz; qN[ct] += zz * zz;
                float pz = __shfl_xor(zz, 1);
                if ((l15 & 1) == 0)
                    zbf[(size_t)(rb + i) * 64 + (n >> 1)] = pk_bf16(zz, pz);
            }
        }
    }
    #pragma unroll
    for (int j = 0; j < 8; ++j) {
        sN[j] += __shfl_xor(sN[j], 16); sN[j] += __shfl_xor(sN[j], 32);
        qN[j] += __shfl_xor(qN[j], 16); qN[j] += __shfl_xor(qN[j], 32);
    }
    if (lane < 16) {
        #pragma unroll
        for (int ct = 0; ct < 8; ++ct) {
            red[0][wave][ct * 16 + lane] = sN[ct];
            red[1][wave][ct * 16 + lane] = qN[ct];
        }
    }
    __syncthreads();
    if (tid < C1) {
        atomicAdd(&stats[tid],
                  red[0][0][tid] + red[0][1][tid] + red[0][2][tid] + red[0][3][tid]);
        atomicAdd(&stats[C1 + tid],
                  red[1][0][tid] + red[1][1][tid] + red[1][2][tid] + red[1][3][tid]);
    }
}

__global__ void k_ab(const float* __restrict__ stats, const float* __restrict__ gamma,
                     const float* __restrict__ beta, float* __restrict__ ab) {
    int t = threadIdx.x;
    if (t < C1) {
        float mu = stats[t] / (float)N_NODES;
        float var = stats[C1 + t] / (float)N_NODES - mu * mu;
        float inv = rsqrtf(var + BN_EPS);
        float a = gamma[t] * inv;
        ab[t] = a;
        ab[C1 + t] = beta[t] - mu * a;
    }
}

// ---------------- output: thread-per-node, wave-uniform scalar weights ----------------
// (k_out4's per-lane d0 broke the s_load broadcast -> 90us. Reverted to this.)

__global__ __launch_bounds__(256) void k_out3(const unsigned* __restrict__ zbf,
                                              const float* __restrict__ ab,
                                              const float* __restrict__ pa,
                                              const float* __restrict__ w2,
                                              const float* __restrict__ b2,
                                              float* __restrict__ out) {
    int v = blockIdx.x * 256 + threadIdx.x;
    if (v >= N_NODES) return;
    float alpha = pa[0];
    float acc[NCLS];
    #pragma unroll
    for (int j = 0; j < NCLS; ++j) acc[j] = b2[j];
    const uint4* zr = (const uint4*)(zbf + (size_t)v * 64);
    #pragma unroll
    for (int pk4 = 0; pk4 < 16; ++pk4) {
        uint4 g = zr[pk4];
        unsigned gw[4] = {g.x, g.y, g.z, g.w};
        #pragma unroll
        for (int w = 0; w < 4; ++w) {
            int d0 = pk4 * 8 + w * 2;
            float p0 = bf_lo(gw[w]) * ab[d0]     + ab[C1 + d0];
            float p1 = bf_hi(gw[w]) * ab[d0 + 1] + ab[C1 + d0 + 1];
            p0 = (p0 > 0.f) ? p0 : alpha * p0;
            p1 = (p1 > 0.f) ? p1 : alpha * p1;
            #pragma unroll
            for (int j = 0; j < NCLS; ++j)
                acc[j] += p0 * w2[d0 * NCLS + j] + p1 * w2[(d0 + 1) * NCLS + j];
        }
    }
    #pragma unroll
    for (int j = 0; j < NCLS; ++j) out[(size_t)v * NCLS + j] = acc[j];
}

// ---------------- host ----------------

extern "C" void kernel_launch(void* const* d_in, const int* in_sizes, int n_in,
                              void* d_out, int out_size, void* d_ws, size_t ws_size,
                              hipStream_t stream) {
    const float* x      = (const float*)d_in[0];
    const float* e      = (const float*)d_in[1];
    const float* c      = (const float*)d_in[2];
    const float* w_node = (const float*)d_in[3];
    const float* b_node = (const float*)d_in[4];
    const float* w_edge = (const float*)d_in[5];
    const float* b_edge = (const float*)d_in[6];
    const float* w_out1 = (const float*)d_in[7];
    const float* b_out1 = (const float*)d_in[8];
    const float* gamma  = (const float*)d_in[9];
    const float* beta   = (const float*)d_in[10];
    const float* pa     = (const float*)d_in[11];
    const float* w_out2 = (const float*)d_in[12];
    const float* b_out2 = (const float*)d_in[13];
    const int*   ei     = (const int*)d_in[14];
    float* out = (float*)d_out;

    char* wsb = (char*)d_ws;
    // Region A (64MB): ebf [bf16 1M x 32] eid order; LIVE until k_aggse completes.
    //   zbf (25.6MB) overlays region A at offset 0 (written in k_zmfma, after
    //   ebf is dead). sebf has its OWN allocation (concurrent with live ebf).
    ushort*   ebf  = (ushort*)wsb;
    unsigned* zbf  = (unsigned*)wsb;
    size_t off = (64000000 + 255) & ~(size_t)255;
    auto alloc = [&](size_t bytes) {
        void* p = wsb + off;
        off = (off + bytes + 255) & ~(size_t)255;
        return p;
    };
    int*      cnt      = (int*)alloc(4ull * N_NODES);   // counts, then cursor
    int*      offs     = (int*)alloc(4ull * (N_NODES + 1));
    float*    dinv     = (float*)alloc(4ull * N_NODES);
    int*      bsum     = (int*)alloc(4ull * 128);
    uint2*    epk      = (uint2*)alloc(8ull * N_EDGES);          // packed CSR (8B)
    float*    stats    = (float*)alloc(4ull * 256);
    float*    ab       = (float*)alloc(4ull * 256);
    unsigned* sebf     = (unsigned*)alloc(4ull * N_NODES * 32);  // se bf16 (own buf!)
    unsigned* hb0      = (unsigned*)alloc(4ull * N_NODES * 32);  // bf16x2 packed
    unsigned* hb1      = (unsigned*)alloc(4ull * N_NODES * 32);
    unsigned* hb2      = (unsigned*)alloc(4ull * N_NODES * 32);
    unsigned* hb3      = (unsigned*)alloc(4ull * N_NODES * 32);
    unsigned* cbf      = (unsigned*)alloc(4ull * N_NODES * 16);  // c in bf16
    uint4*    bpkg     = (uint4*)alloc(16ull * 12 * C1);         // w_out1 B-frag order
    uint4*    bpkn     = (uint4*)alloc(16ull * 16 * HID);        // w_node B-frag order
    unsigned* hsbf     = (unsigned*)alloc(4ull * N_NODES * 32);  // hsum bf16

    hipMemsetAsync(cnt, 0, 4ull * N_NODES, stream);
    hipMemsetAsync(stats, 0, 4ull * 256, stream);

    k_count<<<(N_EDGES + 255) / 256, 256, 0, stream>>>(ei, cnt);
    k_scan1<<<SCAN_B, 1024, 0, stream>>>(cnt, offs, dinv, bsum);
    k_scan2<<<1, 1024, 0, stream>>>(bsum, SCAN_B);
    k_scan3<<<SCAN_B, 1024, 0, stream>>>(bsum, offs, cnt);   // cnt becomes cursor
    k_fill<<<(N_EDGES + 255) / 256, 256, 0, stream>>>(ei, cnt, dinv, epk);

    k_wpack<<<1, 256, 0, stream>>>(w_out1, w_node, bpkg, bpkn);
    k_convm<<<CONV_E_BLOCKS + CONV_C_BLOCKS, 256, 0, stream>>>(
        (const float4*)e, (uint4*)ebf, (const float4*)c, (uint2*)cbf);
    k_aggse<<<N_NODES / 16, 256, 0, stream>>>((const unsigned*)ebf, epk, offs, dinv,
                                              w_edge, b_edge, sebf);

    k_h0m<<<(ZSTRIPS + 3) / 4, 256, 0, stream>>>(x, bpkn, b_node, hb0);

    k_layer4<<<N_NODES * 16 / 256, 256, 0, stream>>>(hb0, sebf, epk, offs, dinv, hb1);
    k_layer4<<<N_NODES * 16 / 256, 256, 0, stream>>>(hb1, sebf, epk, offs, dinv, hb2);
    k_layer4s<<<N_NODES * 16 / 256, 256, 0, stream>>>(hb2, hb0, hb1, sebf, epk, offs,
                                                      dinv, hb3, hsbf);

    k_zmfma<<<(ZSTRIPS + 3) / 4, 256, 0, stream>>>(hsbf, cbf, bpkg, b_out1, zbf, stats);
    k_ab<<<1, 128, 0, stream>>>(stats, gamma, beta, ab);
    k_out3<<<(N_NODES + 255) / 256, 256, 0, stream>>>(zbf, ab, pa, w_out2, b_out2, out);
}